// Round 4
// baseline (2425.818 us; speedup 1.0000x reference)
//
#include <hip/hip_runtime.h>

#define NN 10000
#define NE 100000
#define NG 64
#define RCUT 5.0f
#define FEPS 1e-9f
#define PREF 0.63245553203367586f   /* sqrt(2/RCUT) */
#define PI_R 0.62831853071795864f   /* pi/RCUT */
#define INVK 0.17677669529663687f   /* 1/sqrt(32) */

static __device__ __forceinline__ float sigm(float z){ return 1.0f/(1.0f+__expf(-z)); }

template<int I> struct IC { static constexpr int value = I; };

// ================= CSR build =================
__global__ __launch_bounds__(256) void csr_count(const int* __restrict__ eidx,
                                                 int* __restrict__ deg)
{
    int e = blockIdx.x*256 + threadIdx.x;
    if (e < NE) atomicAdd(&deg[eidx[NE + e]], 1);
}

__global__ __launch_bounds__(256) void csr_scan(const int* __restrict__ deg,
                                                int* __restrict__ roff,
                                                int* __restrict__ woff)
{
    __shared__ int part[256];
    const int tid = threadIdx.x;
    const int C = 40;                 // 256*40 = 10240 >= NN
    int base = tid*C;
    int s = 0;
    for (int j=0;j<C;j++){ int idx=base+j; if (idx<NN) s += deg[idx]; }
    part[tid] = s; __syncthreads();
    for (int off=1; off<256; off<<=1){
        int v = part[tid];
        int add = (tid>=off) ? part[tid-off] : 0;
        __syncthreads();
        part[tid] = v + add;
        __syncthreads();
    }
    int run = (tid==0) ? 0 : part[tid-1];
    for (int j=0;j<C;j++){
        int idx = base+j;
        if (idx < NN){ roff[idx]=run; woff[idx]=run; run += deg[idx]; }
    }
    if (tid==255) roff[NN] = run;
}

__global__ __launch_bounds__(256) void csr_scatter(const int* __restrict__ eidx,
                                                   int* __restrict__ woff,
                                                   int* __restrict__ elist,
                                                   int* __restrict__ einv)
{
    int e = blockIdx.x*256 + threadIdx.x;
    if (e < NE){
        int pos = atomicAdd(&woff[eidx[NE + e]], 1);
        elist[pos] = e;
        einv[e] = pos;
    }
}

// ================= per-edge forward: write msg records (CSR slot order) ======
// msg record (144 floats): [l*32+k] = Rl[l][k]*Zs[k]  (128), [128+lm] = Y[lm]
__global__ __launch_bounds__(256) void edge_compute(
    const float* __restrict__ pos, const int* __restrict__ eidx,
    const float* __restrict__ shifts, const int* __restrict__ species,
    const float* __restrict__ Wz,
    const float* __restrict__ rW1, const float* __restrict__ rb1,
    const float* __restrict__ rW2, const float* __restrict__ rb2,
    const float* __restrict__ rW3, const float* __restrict__ rb3,
    const int* __restrict__ einv, float* __restrict__ msg)
{
    const int e = blockIdx.x*256 + threadIdx.x;
    if (e >= NE) return;
    const int s = eidx[e];
    const int t = eidx[NE + e];
    float vx = pos[3*t+0]-pos[3*s+0]+shifts[3*e+0];
    float vy = pos[3*t+1]-pos[3*s+1]+shifts[3*e+1];
    float vz = pos[3*t+2]-pos[3*s+2]+shifts[3*e+2];
    float r2 = vx*vx+vy*vy+vz*vz + FEPS;
    float r  = sqrtf(r2);
    float inv_r = 1.0f/r;
    float x = vx*inv_r, y = vy*inv_r, z = vz*inv_r;

    float tt = r*(1.0f/RCUT);
    float fc = 0.0f;
    if (r < RCUT){
        float t2=tt*tt, t3=t2*tt, t6=t3*t3;
        fc = 1.0f + t6*(-28.0f + tt*(48.0f - 21.0f*tt));
    }
    float inv_rp = 1.0f/(r+FEPS);
    float w = PREF*fc*inv_rp;
    float s1,c1; __sincosf(PI_R*r, &s1, &c1);
    float xr[8];
    {
        float sp_=0.f, sc=s1; const float c2=2.f*c1;
        #pragma unroll
        for(int m=0;m<8;m++){ xr[m]=sc*w; float nx=c2*sc-sp_; sp_=sc; sc=nx; }
    }
    const int sp = species[s];
    float* mb = msg + (size_t)einv[e]*144;
    #pragma unroll
    for (int l=0;l<4;l++){
        const float* W1 = rW1 + l*256;  const float* B1 = rb1 + l*32;
        float h1[32];
        #pragma unroll
        for(int k=0;k<32;k++){
            float a = B1[k];
            #pragma unroll
            for(int q=0;q<8;q++) a += xr[q]*W1[k*8+q];
            h1[k] = a*sigm(a);
        }
        const float* W2 = rW2 + l*1024; const float* B2 = rb2 + l*32;
        float h2[32];
        #pragma unroll
        for(int j=0;j<32;j++){
            float a = B2[j];
            #pragma unroll
            for(int k=0;k<32;k++) a += h1[k]*W2[j*32+k];
            h2[j] = a*sigm(a);
        }
        const float* W3 = rW3 + l*1024; const float* B3 = rb3 + l*32;
        #pragma unroll
        for(int j=0;j<32;j++){
            float a = B3[j];
            #pragma unroll
            for(int k=0;k<32;k++) a += h2[k]*W3[j*32+k];
            mb[l*32+j] = a * Wz[j*3+sp];
        }
    }
    float* Yp = mb + 128;
    Yp[0]  = 1.0f;
    Yp[1]  = 1.7320508f*x;  Yp[2]  = 1.7320508f*y;  Yp[3]  = 1.7320508f*z;
    Yp[4]  = 3.8729833f*x*y; Yp[5] = 3.8729833f*y*z;
    Yp[6]  = 1.1180340f*(3.f*z*z-1.f);
    Yp[7]  = 3.8729833f*x*z; Yp[8] = 1.9364917f*(x*x-y*y);
    Yp[9]  = 2.0916501f*y*(3.f*x*x-y*y);
    Yp[10] = 10.246951f*x*y*z;
    Yp[11] = 1.6201852f*y*(5.f*z*z-1.f);
    Yp[12] = 1.3228757f*(5.f*z*z*z-3.f*z);
    Yp[13] = 1.6201852f*x*(5.f*z*z-1.f);
    Yp[14] = 5.1234754f*z*(x*x-y*y);
    Yp[15] = 2.0916501f*x*(x*x-3.f*y*y);
}

// ================= gather: one wave per node, sequential msg stream ==========
__global__ __launch_bounds__(256) void gather(
    const float* __restrict__ msg, const int* __restrict__ roff,
    float* __restrict__ A_t)
{
    const int w = (blockIdx.x*256 + threadIdx.x) >> 6;   // node id
    const int lane = threadIdx.x & 63;
    if (w >= NN) return;
    const int k = lane & 31;
    const bool hi = (lane >= 32);
    float a0=0,a1=0,a2=0,a3=0,a4=0,a5=0,a6=0,a7=0;
    const int beg = roff[w], end = roff[w+1];
    for (int idx=beg; idx<end; ++idx){
        const float* b = msg + (size_t)idx*144;
        float rl1 = b[32+k];
        float rl2 = b[64+k];
        float rl3 = b[96+k];
        const float* Yp = b + 128;
        if (!hi){
            float rl0 = b[k];
            a0 += rl0*1.0f;
            a1 += rl1*Yp[2];
            a2 += rl2*Yp[4];
            a3 += rl2*Yp[6];
            a4 += rl2*Yp[8];
            a5 += rl3*Yp[10];
            a6 += rl3*Yp[12];
            a7 += rl3*Yp[14];
        } else {
            a0 += rl1*Yp[1];
            a1 += rl1*Yp[3];
            a2 += rl2*Yp[5];
            a3 += rl2*Yp[7];
            a4 += rl3*Yp[9];
            a5 += rl3*Yp[11];
            a6 += rl3*Yp[13];
            a7 += rl3*Yp[15];
        }
    }
    const int i0 = hi ? 1 : 0;
    A_t[((i0+ 0)*32+k)*NN + w] = a0;
    A_t[((i0+ 2)*32+k)*NN + w] = a1;
    A_t[((i0+ 4)*32+k)*NN + w] = a2;
    A_t[((i0+ 6)*32+k)*NN + w] = a3;
    A_t[((i0+ 8)*32+k)*NN + w] = a4;
    A_t[((i0+10)*32+k)*NN + w] = a5;
    A_t[((i0+12)*32+k)*NN + w] = a6;
    A_t[((i0+14)*32+k)*NN + w] = a7;
}

// ================= node pass =================
template<bool NM>
__global__ __launch_bounds__(256) void node_pass(
    const float* __restrict__ A_t, const int* __restrict__ species,
    const float* __restrict__ mixW, const float* __restrict__ symW1,
    const float* __restrict__ symW2, const float* __restrict__ eW,
    const float* __restrict__ ebp, const float* __restrict__ e0W,
    const float* __restrict__ e0b,
    float* __restrict__ dA, float* __restrict__ E_node)
{
    const int n = blockIdx.x*256 + threadIdx.x;
    const int i = blockIdx.y;
    const int l = (i==0)?0 : (i<4)?1 : (i<9)?2 : 3;
    const bool valid = (n < NN);
    const int nn = valid ? n : 0;
    const int sp = species[nn];

    float a[32];
    #pragma unroll
    for(int k=0;k<32;k++) a[k] = A_t[(i*32+k)*NN + nn];

    const float* M = mixW + l*1024;
    float A2[32];
    #pragma unroll
    for(int o=0;o<32;o++){
        float acc = 0.f;
        #pragma unroll
        for(int k=0;k<32;k++) acc += a[k]*M[o*32+k];
        A2[o] = acc*INVK;
    }
    const float nl = (l==0)?1.0f : (l==1)?0.57735027f : (l==2)?0.44721360f : 0.37796447f;
    float ce = 0.f;
    float dA2[32];
    #pragma unroll
    for(int o=0;o<32;o++){
        float w2v = symW2[(sp*4+l)*32+o];
        float ew  = eW[o];
        float c = A2[o]*A2[o]*nl*w2v;
        float g = 2.f*A2[o]*nl*w2v;
        if (i==0){ float w1v = symW1[sp*32+o]; c += w1v*A2[o]; g += w1v; }
        ce += c*ew;
        dA2[o] = g*ew;
    }
    if (i==0) ce += ebp[0] + e0W[sp] + e0b[0];

    #pragma unroll
    for(int k=0;k<32;k++){
        float acc = 0.f;
        #pragma unroll
        for(int o=0;o<32;o++) acc += dA2[o]*M[o*32+k];
        if (valid){
            if (NM) dA[(size_t)n*512 + i*32 + k] = acc*INVK;
            else    dA[(i*32+k)*NN + n]          = acc*INVK;
        }
    }
    if (valid) atomicAdd(&E_node[n], ce);
}

// ================= E binning (batch sorted -> wave-segmented reduce) =========
__global__ __launch_bounds__(256) void ereduce(
    const float* __restrict__ E_node, const int* __restrict__ batch,
    float* __restrict__ out)
{
    int n = blockIdx.x*256 + threadIdx.x;
    const int lane = threadIdx.x & 63;
    float v = (n < NN) ? E_node[n] : 0.f;
    int   b = (n < NN) ? batch[n]  : -1;
    #pragma unroll
    for (int d=1; d<64; d<<=1){
        float pv = __shfl_down(v, d, 64);
        int   pb = __shfl_down(b, d, 64);
        if ((lane + d) < 64 && pb == b) v += pv;
    }
    int prevb = __shfl_up(b, 1, 64);
    if (n < NN && (lane == 0 || prevb != b)) atomicAdd(&out[b], v);
}

// ================= fused edge backward (all 4 l in one thread) ===============
// NM=true : idx walks CSR order (e=elist[idx]); dA node-major (dA+t*512);
//           t-side force via wave-segmented reduce (t sorted), s-side atomics
// NM=false: fallback, e=idx, dA strided [(i*32+k)*NN+t], direct atomics
template<bool NM>
__global__ __launch_bounds__(256, 3) void edge_bwd_f(
    const float* __restrict__ pos, const int* __restrict__ eidx,
    const float* __restrict__ shifts, const int* __restrict__ species,
    const float* __restrict__ Wz,
    const float* __restrict__ rW1, const float* __restrict__ rb1,
    const float* __restrict__ rW2, const float* __restrict__ rb2,
    const float* __restrict__ rW3, const float* __restrict__ rb3,
    const float* __restrict__ dA, const int* __restrict__ elist,
    float* __restrict__ F)
{
    const int idx0 = blockIdx.x*256 + threadIdx.x;
    const bool valid = (idx0 < NE);
    const int idx = valid ? idx0 : (NE-1);     // clamp: keep all lanes active for shuffles
    const int e = NM ? elist[idx] : idx;
    const int s = eidx[e];
    const int t = eidx[NE + e];
    float vx = pos[3*t+0]-pos[3*s+0]+shifts[3*e+0];
    float vy = pos[3*t+1]-pos[3*s+1]+shifts[3*e+1];
    float vz = pos[3*t+2]-pos[3*s+2]+shifts[3*e+2];
    float r2 = vx*vx+vy*vy+vz*vz + FEPS;
    float r  = sqrtf(r2);
    float inv_r = 1.0f/r;
    float x = vx*inv_r, y = vy*inv_r, z = vz*inv_r;

    float tt = r*(1.0f/RCUT);
    float fc = 0.0f, dfc = 0.0f;
    if (r < RCUT){
        float t2=tt*tt, t3=t2*tt, t5=t3*t2, t6=t5*tt, t7=t6*tt;
        fc  = 1.0f + t6*(-28.0f + tt*(48.0f - 21.0f*tt));
        dfc = (-168.f*t5 + 336.f*t6 - 168.f*t7)*(1.0f/RCUT);
    }
    float inv_rp = 1.0f/(r+FEPS);
    float w = PREF*fc*inv_rp;
    float s1,c1; __sincosf(PI_R*r, &s1, &c1);
    float sn[8], cn[8];
    {
        float sp_=0.f, sc=s1, cp_=1.f, cc=c1; const float c2=2.f*c1;
        #pragma unroll
        for(int m=0;m<8;m++){
            sn[m]=sc; cn[m]=cc;
            float nx=c2*sc-sp_; sp_=sc; sc=nx;
            float ncx=c2*cc-cp_; cp_=cc; cc=ncx;
        }
    }
    const int sp = species[s];
    const float* dAr = NM ? (dA + (size_t)t*512) : dA;

    float dux=0.f, duy=0.f, duz=0.f, gr=0.f;

    auto run_l = [&](auto LC){
        constexpr int l = decltype(LC)::value;
        const float* W1 = rW1 + l*256;  const float* B1 = rb1 + l*32;
        float df1[32], h1[32];
        #pragma unroll
        for(int k=0;k<32;k++){
            float a = B1[k];
            #pragma unroll
            for(int q=0;q<8;q++) a += (sn[q]*w)*W1[k*8+q];
            float sg=sigm(a); h1[k]=a*sg; df1[k]=sg*(1.f + a*(1.f-sg));
        }
        const float* W2 = rW2 + l*1024; const float* B2 = rb2 + l*32;
        float df2[32], h2[32];
        #pragma unroll
        for(int j=0;j<32;j++){
            float a = B2[j];
            #pragma unroll
            for(int k=0;k<32;k++) a += h1[k]*W2[j*32+k];
            float sg=sigm(a); h2[j]=a*sg; df2[j]=sg*(1.f + a*(1.f-sg));
        }
        const float* W3 = rW3 + l*1024; const float* B3 = rb3 + l*32;
        float RlZ[32];
        #pragma unroll
        for(int j=0;j<32;j++){
            float a = B3[j];
            #pragma unroll
            for(int k=0;k<32;k++) a += h2[k]*W3[j*32+k];
            RlZ[j] = a * Wz[j*3+sp];
        }
        float dRlZ[32];
        #pragma unroll
        for(int k=0;k<32;k++) dRlZ[k]=0.f;
        #define ROW(I, YV, DX, DY, DZ) { \
            const float yv=(YV); float dY=0.f; \
            _Pragma("unroll") \
            for(int k=0;k<32;k++){ \
                float g = NM ? dAr[(I)*32+k] : dAr[((I)*32+k)*NN + t]; \
                dRlZ[k] += g*yv; dY += g*RlZ[k]; } \
            dux += dY*(DX); duy += dY*(DY); duz += dY*(DZ); }
        if constexpr (l==0){
            ROW(0, 1.0f, 0.f,0.f,0.f)
        } else if constexpr (l==1){
            ROW(1, 1.7320508f*x, 1.7320508f, 0.f, 0.f)
            ROW(2, 1.7320508f*y, 0.f, 1.7320508f, 0.f)
            ROW(3, 1.7320508f*z, 0.f, 0.f, 1.7320508f)
        } else if constexpr (l==2){
            ROW(4, 3.8729833f*x*y, 3.8729833f*y, 3.8729833f*x, 0.f)
            ROW(5, 3.8729833f*y*z, 0.f, 3.8729833f*z, 3.8729833f*y)
            ROW(6, 1.1180340f*(3.f*z*z-1.f), 0.f, 0.f, 6.7082039f*z)
            ROW(7, 3.8729833f*x*z, 3.8729833f*z, 0.f, 3.8729833f*x)
            ROW(8, 1.9364917f*(x*x-y*y), 3.8729833f*x, -3.8729833f*y, 0.f)
        } else {
            ROW(9,  2.0916501f*y*(3.f*x*x-y*y), 12.549901f*x*y, 2.0916501f*(3.f*x*x-3.f*y*y), 0.f)
            ROW(10, 10.246951f*x*y*z, 10.246951f*y*z, 10.246951f*x*z, 10.246951f*x*y)
            ROW(11, 1.6201852f*y*(5.f*z*z-1.f), 0.f, 1.6201852f*(5.f*z*z-1.f), 16.201852f*y*z)
            ROW(12, 1.3228757f*(5.f*z*z*z-3.f*z), 0.f, 0.f, 1.3228757f*(15.f*z*z-3.f))
            ROW(13, 1.6201852f*x*(5.f*z*z-1.f), 1.6201852f*(5.f*z*z-1.f), 0.f, 16.201852f*x*z)
            ROW(14, 5.1234754f*z*(x*x-y*y), 10.246951f*x*z, -10.246951f*y*z, 5.1234754f*(x*x-y*y))
            ROW(15, 2.0916501f*x*(x*x-3.f*y*y), 2.0916501f*(3.f*x*x-3.f*y*y), -12.549901f*x*y, 0.f)
        }
        #undef ROW
        #pragma unroll
        for(int j=0;j<32;j++) dRlZ[j] *= Wz[j*3+sp];
        float dz2[32];
        #pragma unroll
        for(int k=0;k<32;k++){
            float a=0.f;
            #pragma unroll
            for(int j=0;j<32;j++) a += dRlZ[j]*W3[j*32+k];
            dz2[k] = a*df2[k];
        }
        float dz1[32];
        #pragma unroll
        for(int k=0;k<32;k++){
            float a=0.f;
            #pragma unroll
            for(int j=0;j<32;j++) a += dz2[j]*W2[j*32+k];
            dz1[k] = a*df1[k];
        }
        #pragma unroll
        for(int m=0;m<8;m++){
            float a=0.f;
            #pragma unroll
            for(int k=0;k<32;k++) a += dz1[k]*W1[k*8+m];
            float b  = PREF*sn[m]*inv_rp;
            float db = PREF*((float)(m+1)*PI_R*cn[m]*(r+FEPS) - sn[m])*inv_rp*inv_rp;
            gr += a*(db*fc + b*dfc);
        }
    };
    run_l(IC<0>{});
    run_l(IC<1>{});
    run_l(IC<2>{});
    run_l(IC<3>{});

    float udd = x*dux + y*duy + z*duz;
    float gx = gr*x + (dux - x*udd)*inv_r;
    float gy = gr*y + (duy - y*udd)*inv_r;
    float gz = gr*z + (duz - z*udd)*inv_r;
    if (!valid){ gx=0.f; gy=0.f; gz=0.f; }

    if (NM){
        // s-side: scattered atomics with the per-edge value
        if (valid){
            atomicAdd(&F[3*s+0], gx); atomicAdd(&F[3*s+1], gy); atomicAdd(&F[3*s+2], gz);
        }
        // t-side: equal-t runs are contiguous in CSR order -> segmented suffix sum
        const int lane = threadIdx.x & 63;
        int key = valid ? t : -1;
        float rx=gx, ry=gy, rz=gz;
        #pragma unroll
        for (int d=1; d<64; d<<=1){
            float px = __shfl_down(rx, d, 64);
            float py = __shfl_down(ry, d, 64);
            float pz = __shfl_down(rz, d, 64);
            int   pk = __shfl_down(key, d, 64);
            if ((lane + d) < 64 && pk == key){ rx+=px; ry+=py; rz+=pz; }
        }
        int pk = __shfl_up(key, 1, 64);
        if (valid && (lane == 0 || pk != key)){
            atomicAdd(&F[3*t+0], -rx); atomicAdd(&F[3*t+1], -ry); atomicAdd(&F[3*t+2], -rz);
        }
    } else {
        if (valid){
            atomicAdd(&F[3*t+0], -gx); atomicAdd(&F[3*t+1], -gy); atomicAdd(&F[3*t+2], -gz);
            atomicAdd(&F[3*s+0],  gx); atomicAdd(&F[3*s+1],  gy); atomicAdd(&F[3*s+2],  gz);
        }
    }
}

// ================= fallback: round-1 atomic edge forward =====================
__global__ __launch_bounds__(256) void edge_fwd_fb(
    const float* __restrict__ pos, const int* __restrict__ eidx,
    const float* __restrict__ shifts, const int* __restrict__ species,
    const float* __restrict__ Wz,
    const float* __restrict__ rW1, const float* __restrict__ rb1,
    const float* __restrict__ rW2, const float* __restrict__ rb2,
    const float* __restrict__ rW3, const float* __restrict__ rb3,
    float* __restrict__ A_t)
{
    const int e = blockIdx.x*256 + threadIdx.x;
    const int l = blockIdx.y;
    if (e >= NE) return;
    const int s = eidx[e];
    const int t = eidx[NE + e];
    float vx = pos[3*t+0]-pos[3*s+0]+shifts[3*e+0];
    float vy = pos[3*t+1]-pos[3*s+1]+shifts[3*e+1];
    float vz = pos[3*t+2]-pos[3*s+2]+shifts[3*e+2];
    float r2 = vx*vx+vy*vy+vz*vz + FEPS;
    float r  = sqrtf(r2);
    float inv_r = 1.0f/r;
    float x = vx*inv_r, y = vy*inv_r, z = vz*inv_r;
    float tt = r*(1.0f/RCUT);
    float fcv = 0.0f;
    if (r < RCUT){
        float t2=tt*tt, t3=t2*tt, t6=t3*t3;
        fcv = 1.0f + t6*(-28.0f + tt*(48.0f - 21.0f*tt));
    }
    float inv_rp = 1.0f/(r+FEPS);
    float w = PREF*fcv*inv_rp;
    float s1,c1; __sincosf(PI_R*r, &s1, &c1);
    float xr[8];
    {
        float sp_=0.f, sc=s1; const float c2=2.f*c1;
        #pragma unroll
        for(int m=0;m<8;m++){ xr[m]=sc*w; float nx=c2*sc-sp_; sp_=sc; sc=nx; }
    }
    const float* W1 = rW1 + l*256;  const float* B1 = rb1 + l*32;
    float h1[32];
    #pragma unroll
    for(int k=0;k<32;k++){
        float a = B1[k];
        #pragma unroll
        for(int q=0;q<8;q++) a += xr[q]*W1[k*8+q];
        h1[k] = a*sigm(a);
    }
    const float* W2 = rW2 + l*1024; const float* B2 = rb2 + l*32;
    float h2[32];
    #pragma unroll
    for(int j=0;j<32;j++){
        float a = B2[j];
        #pragma unroll
        for(int k=0;k<32;k++) a += h1[k]*W2[j*32+k];
        h2[j] = a*sigm(a);
    }
    const float* W3 = rW3 + l*1024; const float* B3 = rb3 + l*32;
    const int sp = species[s];
    float RlZ[32];
    #pragma unroll
    for(int j=0;j<32;j++){
        float a = B3[j];
        #pragma unroll
        for(int k=0;k<32;k++) a += h2[k]*W3[j*32+k];
        RlZ[j] = a * Wz[j*3+sp];
    }
    #define ACCI(I, YV) { const float yv=(YV); \
        _Pragma("unroll") \
        for(int k=0;k<32;k++) atomicAdd(&A_t[((I)*32+k)*NN + t], RlZ[k]*yv); }
    if (l==0){
        ACCI(0, 1.0f)
    } else if (l==1){
        ACCI(1, 1.7320508f*x) ACCI(2, 1.7320508f*y) ACCI(3, 1.7320508f*z)
    } else if (l==2){
        ACCI(4, 3.8729833f*x*y) ACCI(5, 3.8729833f*y*z)
        ACCI(6, 1.1180340f*(3.f*z*z-1.f)) ACCI(7, 3.8729833f*x*z)
        ACCI(8, 1.9364917f*(x*x-y*y))
    } else {
        ACCI(9,  2.0916501f*y*(3.f*x*x-y*y))
        ACCI(10, 10.246951f*x*y*z)
        ACCI(11, 1.6201852f*y*(5.f*z*z-1.f))
        ACCI(12, 1.3228757f*(5.f*z*z*z-3.f*z))
        ACCI(13, 1.6201852f*x*(5.f*z*z-1.f))
        ACCI(14, 5.1234754f*z*(x*x-y*y))
        ACCI(15, 2.0916501f*x*(x*x-3.f*y*y))
    }
    #undef ACCI
}

// ================= launcher =================
extern "C" void kernel_launch(void* const* d_in, const int* in_sizes, int n_in,
                              void* d_out, int out_size, void* d_ws, size_t ws_size,
                              hipStream_t stream)
{
    const float* pos    = (const float*)d_in[0];
    const int*   eidx   = (const int*)  d_in[1];
    const float* shifts = (const float*)d_in[2];
    const int*   spec   = (const int*)  d_in[3];
    const int*   batch  = (const int*)  d_in[4];
    const float* Wz     = (const float*)d_in[5];
    const float* rW1    = (const float*)d_in[6];
    const float* rb1    = (const float*)d_in[7];
    const float* rW2    = (const float*)d_in[8];
    const float* rb2    = (const float*)d_in[9];
    const float* rW3    = (const float*)d_in[10];
    const float* rb3    = (const float*)d_in[11];
    const float* mixW   = (const float*)d_in[12];
    const float* symW1  = (const float*)d_in[13];
    const float* symW2  = (const float*)d_in[14];
    const float* eW     = (const float*)d_in[15];
    const float* ebp    = (const float*)d_in[16];
    const float* e0W    = (const float*)d_in[17];
    const float* e0b    = (const float*)d_in[18];
    float* out = (float*)d_out;

    // workspace: ints [deg NN | roff NN+1 | woff NN | elist NE | einv NE],
    // floats [A_t 512*NN | E_node NN | msg 144*NE]; dA_n (512*NN) aliases msg
    const size_t INTS   = (size_t)(3*NN + 1 + 2*NE);
    const size_t FOFF   = ((INTS*4 + 255)/256)*256;
    const size_t NEEDED = FOFF + ((size_t)512*NN + NN + (size_t)144*NE)*4;

    if (ws_size >= NEEDED){
        int*   deg    = (int*)d_ws;
        int*   roff   = deg + NN;
        int*   woff   = roff + NN + 1;
        int*   elist  = woff + NN;
        int*   einv   = elist + NE;
        float* f0     = (float*)((char*)d_ws + FOFF);
        float* A_t    = f0;
        float* E_node = A_t + (size_t)512*NN;
        float* msg    = E_node + NN;
        float* dA_n   = msg;            // alias: msg dead after gather

        hipMemsetAsync(deg, 0, NN*sizeof(int), stream);
        hipMemsetAsync(E_node, 0, NN*sizeof(float), stream);
        hipMemsetAsync(d_out, 0, (size_t)out_size*sizeof(float), stream);

        csr_count  <<<(NE+255)/256, 256, 0, stream>>>(eidx, deg);
        csr_scan   <<<1, 256, 0, stream>>>(deg, roff, woff);
        csr_scatter<<<(NE+255)/256, 256, 0, stream>>>(eidx, woff, elist, einv);
        edge_compute<<<(NE+255)/256, 256, 0, stream>>>(pos, eidx, shifts, spec, Wz,
                                                       rW1, rb1, rW2, rb2, rW3, rb3,
                                                       einv, msg);
        gather<<<(NN*64+255)/256, 256, 0, stream>>>(msg, roff, A_t);
        dim3 ng((NN+255)/256, 16);
        node_pass<true><<<ng, 256, 0, stream>>>(A_t, spec, mixW, symW1, symW2,
                                                eW, ebp, e0W, e0b, dA_n, E_node);
        ereduce<<<(NN+255)/256, 256, 0, stream>>>(E_node, batch, out);
        edge_bwd_f<true><<<(NE+255)/256, 256, 0, stream>>>(pos, eidx, shifts, spec, Wz,
                                                           rW1, rb1, rW2, rb2, rW3, rb3,
                                                           dA_n, elist, out + NG);
    } else {
        // fallback: round-1-style path (requires 41 MB, known-good)
        float* A_t    = (float*)d_ws;
        float* E_node = A_t + (size_t)512*NN;
        float* dA_t   = E_node + NN;
        hipMemsetAsync(d_ws, 0, ((size_t)512*NN + NN)*sizeof(float), stream);
        hipMemsetAsync(d_out, 0, (size_t)out_size*sizeof(float), stream);
        dim3 eg((NE+255)/256, 4);
        edge_fwd_fb<<<eg, 256, 0, stream>>>(pos, eidx, shifts, spec, Wz,
                                            rW1, rb1, rW2, rb2, rW3, rb3, A_t);
        dim3 ng((NN+255)/256, 16);
        node_pass<false><<<ng, 256, 0, stream>>>(A_t, spec, mixW, symW1, symW2,
                                                 eW, ebp, e0W, e0b, dA_t, E_node);
        ereduce<<<(NN+255)/256, 256, 0, stream>>>(E_node, batch, out);
        edge_bwd_f<false><<<(NE+255)/256, 256, 0, stream>>>(pos, eidx, shifts, spec, Wz,
                                                            rW1, rb1, rW2, rb2, rW3, rb3,
                                                            dA_t, nullptr, out + NG);
    }
}

// Round 5
// 532.585 us; speedup vs baseline: 4.5548x; 4.5548x over previous
//
#include <hip/hip_runtime.h>

#define NN 10000
#define NE 100000
#define NG 64
#define RCUT 5.0f
#define FEPS 1e-9f
#define PREF 0.63245553203367586f   /* sqrt(2/RCUT) */
#define PI_R 0.62831853071795864f   /* pi/RCUT */
#define INVK 0.17677669529663687f   /* 1/sqrt(32) */

static __device__ __forceinline__ float sigm(float z){ return 1.0f/(1.0f+__expf(-z)); }

// ================= CSR build =================
__global__ __launch_bounds__(256) void csr_count(const int* __restrict__ eidx,
                                                 int* __restrict__ deg)
{
    int e = blockIdx.x*256 + threadIdx.x;
    if (e < NE) atomicAdd(&deg[eidx[NE + e]], 1);
}

__global__ __launch_bounds__(256) void csr_scan(const int* __restrict__ deg,
                                                int* __restrict__ roff,
                                                int* __restrict__ woff)
{
    __shared__ int part[256];
    const int tid = threadIdx.x;
    const int C = 40;                 // 256*40 = 10240 >= NN
    int base = tid*C;
    int s = 0;
    for (int j=0;j<C;j++){ int idx=base+j; if (idx<NN) s += deg[idx]; }
    part[tid] = s; __syncthreads();
    for (int off=1; off<256; off<<=1){
        int v = part[tid];
        int add = (tid>=off) ? part[tid-off] : 0;
        __syncthreads();
        part[tid] = v + add;
        __syncthreads();
    }
    int run = (tid==0) ? 0 : part[tid-1];
    for (int j=0;j<C;j++){
        int idx = base+j;
        if (idx < NN){ roff[idx]=run; woff[idx]=run; run += deg[idx]; }
    }
    if (tid==255) roff[NN] = run;
}

__global__ __launch_bounds__(256) void csr_scatter(const int* __restrict__ eidx,
                                                   int* __restrict__ woff,
                                                   int* __restrict__ elist,
                                                   int* __restrict__ einv)
{
    int e = blockIdx.x*256 + threadIdx.x;
    if (e < NE){
        int pos = atomicAdd(&woff[eidx[NE + e]], 1);
        elist[pos] = e;
        einv[e] = pos;
    }
}

// ================= per-edge forward: write msg records (CSR slot order) ======
// msg record (144 floats): [l*32+k] = Rl[l][k]*Zs[k]  (128), [128+lm] = Y[lm]
__global__ __launch_bounds__(256) void edge_compute(
    const float* __restrict__ pos, const int* __restrict__ eidx,
    const float* __restrict__ shifts, const int* __restrict__ species,
    const float* __restrict__ Wz,
    const float* __restrict__ rW1, const float* __restrict__ rb1,
    const float* __restrict__ rW2, const float* __restrict__ rb2,
    const float* __restrict__ rW3, const float* __restrict__ rb3,
    const int* __restrict__ einv, float* __restrict__ msg)
{
    const int e = blockIdx.x*256 + threadIdx.x;
    if (e >= NE) return;
    const int s = eidx[e];
    const int t = eidx[NE + e];
    float vx = pos[3*t+0]-pos[3*s+0]+shifts[3*e+0];
    float vy = pos[3*t+1]-pos[3*s+1]+shifts[3*e+1];
    float vz = pos[3*t+2]-pos[3*s+2]+shifts[3*e+2];
    float r2 = vx*vx+vy*vy+vz*vz + FEPS;
    float r  = sqrtf(r2);
    float inv_r = 1.0f/r;
    float x = vx*inv_r, y = vy*inv_r, z = vz*inv_r;

    float tt = r*(1.0f/RCUT);
    float fc = 0.0f;
    if (r < RCUT){
        float t2=tt*tt, t3=t2*tt, t6=t3*t3;
        fc = 1.0f + t6*(-28.0f + tt*(48.0f - 21.0f*tt));
    }
    float inv_rp = 1.0f/(r+FEPS);
    float w = PREF*fc*inv_rp;
    float s1,c1; __sincosf(PI_R*r, &s1, &c1);
    float xr[8];
    {
        float sp_=0.f, sc=s1; const float c2=2.f*c1;
        #pragma unroll
        for(int m=0;m<8;m++){ xr[m]=sc*w; float nx=c2*sc-sp_; sp_=sc; sc=nx; }
    }
    const int sp = species[s];
    float* mb = msg + (size_t)einv[e]*144;
    #pragma unroll
    for (int l=0;l<4;l++){
        const float* W1 = rW1 + l*256;  const float* B1 = rb1 + l*32;
        float h1[32];
        #pragma unroll
        for(int k=0;k<32;k++){
            float a = B1[k];
            #pragma unroll
            for(int q=0;q<8;q++) a += xr[q]*W1[k*8+q];
            h1[k] = a*sigm(a);
        }
        const float* W2 = rW2 + l*1024; const float* B2 = rb2 + l*32;
        float h2[32];
        #pragma unroll
        for(int j=0;j<32;j++){
            float a = B2[j];
            #pragma unroll
            for(int k=0;k<32;k++) a += h1[k]*W2[j*32+k];
            h2[j] = a*sigm(a);
        }
        const float* W3 = rW3 + l*1024; const float* B3 = rb3 + l*32;
        #pragma unroll
        for(int j=0;j<32;j++){
            float a = B3[j];
            #pragma unroll
            for(int k=0;k<32;k++) a += h2[k]*W3[j*32+k];
            mb[l*32+j] = a * Wz[j*3+sp];
        }
    }
    float* Yp = mb + 128;
    Yp[0]  = 1.0f;
    Yp[1]  = 1.7320508f*x;  Yp[2]  = 1.7320508f*y;  Yp[3]  = 1.7320508f*z;
    Yp[4]  = 3.8729833f*x*y; Yp[5] = 3.8729833f*y*z;
    Yp[6]  = 1.1180340f*(3.f*z*z-1.f);
    Yp[7]  = 3.8729833f*x*z; Yp[8] = 1.9364917f*(x*x-y*y);
    Yp[9]  = 2.0916501f*y*(3.f*x*x-y*y);
    Yp[10] = 10.246951f*x*y*z;
    Yp[11] = 1.6201852f*y*(5.f*z*z-1.f);
    Yp[12] = 1.3228757f*(5.f*z*z*z-3.f*z);
    Yp[13] = 1.6201852f*x*(5.f*z*z-1.f);
    Yp[14] = 5.1234754f*z*(x*x-y*y);
    Yp[15] = 2.0916501f*x*(x*x-3.f*y*y);
}

// ================= gather: one wave per node, sequential msg stream ==========
__global__ __launch_bounds__(256) void gather(
    const float* __restrict__ msg, const int* __restrict__ roff,
    float* __restrict__ A_t)
{
    const int w = (blockIdx.x*256 + threadIdx.x) >> 6;   // node id
    const int lane = threadIdx.x & 63;
    if (w >= NN) return;
    const int k = lane & 31;
    const bool hi = (lane >= 32);
    float a0=0,a1=0,a2=0,a3=0,a4=0,a5=0,a6=0,a7=0;
    const int beg = roff[w], end = roff[w+1];
    for (int idx=beg; idx<end; ++idx){
        const float* b = msg + (size_t)idx*144;
        float rl1 = b[32+k];
        float rl2 = b[64+k];
        float rl3 = b[96+k];
        const float* Yp = b + 128;
        if (!hi){
            float rl0 = b[k];
            a0 += rl0*1.0f;
            a1 += rl1*Yp[2];
            a2 += rl2*Yp[4];
            a3 += rl2*Yp[6];
            a4 += rl2*Yp[8];
            a5 += rl3*Yp[10];
            a6 += rl3*Yp[12];
            a7 += rl3*Yp[14];
        } else {
            a0 += rl1*Yp[1];
            a1 += rl1*Yp[3];
            a2 += rl2*Yp[5];
            a3 += rl2*Yp[7];
            a4 += rl3*Yp[9];
            a5 += rl3*Yp[11];
            a6 += rl3*Yp[13];
            a7 += rl3*Yp[15];
        }
    }
    const int i0 = hi ? 1 : 0;
    A_t[((i0+ 0)*32+k)*NN + w] = a0;
    A_t[((i0+ 2)*32+k)*NN + w] = a1;
    A_t[((i0+ 4)*32+k)*NN + w] = a2;
    A_t[((i0+ 6)*32+k)*NN + w] = a3;
    A_t[((i0+ 8)*32+k)*NN + w] = a4;
    A_t[((i0+10)*32+k)*NN + w] = a5;
    A_t[((i0+12)*32+k)*NN + w] = a6;
    A_t[((i0+14)*32+k)*NN + w] = a7;
}

// ================= node pass =================
template<bool NM>
__global__ __launch_bounds__(256) void node_pass(
    const float* __restrict__ A_t, const int* __restrict__ species,
    const float* __restrict__ mixW, const float* __restrict__ symW1,
    const float* __restrict__ symW2, const float* __restrict__ eW,
    const float* __restrict__ ebp, const float* __restrict__ e0W,
    const float* __restrict__ e0b,
    float* __restrict__ dA, float* __restrict__ E_node)
{
    const int n = blockIdx.x*256 + threadIdx.x;
    const int i = blockIdx.y;
    const int l = (i==0)?0 : (i<4)?1 : (i<9)?2 : 3;
    const bool valid = (n < NN);
    const int nn = valid ? n : 0;
    const int sp = species[nn];

    float a[32];
    #pragma unroll
    for(int k=0;k<32;k++) a[k] = A_t[(i*32+k)*NN + nn];

    const float* M = mixW + l*1024;
    float A2[32];
    #pragma unroll
    for(int o=0;o<32;o++){
        float acc = 0.f;
        #pragma unroll
        for(int k=0;k<32;k++) acc += a[k]*M[o*32+k];
        A2[o] = acc*INVK;
    }
    const float nl = (l==0)?1.0f : (l==1)?0.57735027f : (l==2)?0.44721360f : 0.37796447f;
    float ce = 0.f;
    float dA2[32];
    #pragma unroll
    for(int o=0;o<32;o++){
        float w2v = symW2[(sp*4+l)*32+o];
        float ew  = eW[o];
        float c = A2[o]*A2[o]*nl*w2v;
        float g = 2.f*A2[o]*nl*w2v;
        if (i==0){ float w1v = symW1[sp*32+o]; c += w1v*A2[o]; g += w1v; }
        ce += c*ew;
        dA2[o] = g*ew;
    }
    if (i==0) ce += ebp[0] + e0W[sp] + e0b[0];

    #pragma unroll
    for(int k=0;k<32;k++){
        float acc = 0.f;
        #pragma unroll
        for(int o=0;o<32;o++) acc += dA2[o]*M[o*32+k];
        if (valid){
            if (NM) dA[(size_t)n*512 + i*32 + k] = acc*INVK;
            else    dA[(i*32+k)*NN + n]          = acc*INVK;
        }
    }
    if (valid) atomicAdd(&E_node[n], ce);
}

// ================= E binning (batch sorted -> wave-segmented reduce) =========
__global__ __launch_bounds__(256) void ereduce(
    const float* __restrict__ E_node, const int* __restrict__ batch,
    float* __restrict__ out)
{
    int n = blockIdx.x*256 + threadIdx.x;
    const int lane = threadIdx.x & 63;
    float v = (n < NN) ? E_node[n] : 0.f;
    int   b = (n < NN) ? batch[n]  : -1;
    #pragma unroll
    for (int d=1; d<64; d<<=1){
        float pv = __shfl_down(v, d, 64);
        int   pb = __shfl_down(b, d, 64);
        if ((lane + d) < 64 && pb == b) v += pv;
    }
    int prevb = __shfl_up(b, 1, 64);
    if (n < NN && (lane == 0 || prevb != b)) atomicAdd(&out[b], v);
}

// ================= edge backward (per-l planes, XCD-chunked swizzle) =========
// NM=true : 1D grid of NXB*4 blocks. Flat block id -> bijective XCD-chunk
//           remap -> work g; x = g>>2 (CSR idx block), l = g&3. All 4 l's of
//           a t-chunk stay on ONE XCD -> dA stays L2-resident (2.5 MB/XCD).
//           e=elist[idx]; dA node-major; per-(idx,l) force to fbuf.
// NM=false: fallback, 2D grid (x, l), e=idx, dA strided, direct atomics.
#define NXB ((NE+255)/256)     /* 391 */
template<bool NM>
__global__ __launch_bounds__(256, 3) void edge_bwd(
    const float* __restrict__ pos, const int* __restrict__ eidx,
    const float* __restrict__ shifts, const int* __restrict__ species,
    const float* __restrict__ Wz,
    const float* __restrict__ rW1, const float* __restrict__ rb1,
    const float* __restrict__ rW2, const float* __restrict__ rb2,
    const float* __restrict__ rW3, const float* __restrict__ rb3,
    const float* __restrict__ dA, const int* __restrict__ elist,
    float* __restrict__ fout)
{
    int xb, l;
    if (NM){
        const int nwg = NXB*4;            // 1564
        const int q = nwg/8, r = nwg%8;   // 195, 4
        const int bid = blockIdx.x;
        const int xcd = bid & 7, p = bid >> 3;
        const int g = (xcd < r ? xcd*(q+1) : r*(q+1) + (xcd-r)*q) + p;
        xb = g >> 2; l = g & 3;
    } else {
        xb = blockIdx.x; l = blockIdx.y;
    }
    const int idx = xb*256 + threadIdx.x;
    if (idx >= NE) return;
    const int e = NM ? elist[idx] : idx;
    const int s = eidx[e];
    const int t = eidx[NE + e];
    float vx = pos[3*t+0]-pos[3*s+0]+shifts[3*e+0];
    float vy = pos[3*t+1]-pos[3*s+1]+shifts[3*e+1];
    float vz = pos[3*t+2]-pos[3*s+2]+shifts[3*e+2];
    float r2 = vx*vx+vy*vy+vz*vz + FEPS;
    float r  = sqrtf(r2);
    float inv_r = 1.0f/r;
    float x = vx*inv_r, y = vy*inv_r, z = vz*inv_r;

    float tt = r*(1.0f/RCUT);
    float fc = 0.0f, dfc = 0.0f;
    if (r < RCUT){
        float t2=tt*tt, t3=t2*tt, t5=t3*t2, t6=t5*tt, t7=t6*tt;
        fc  = 1.0f + t6*(-28.0f + tt*(48.0f - 21.0f*tt));
        dfc = (-168.f*t5 + 336.f*t6 - 168.f*t7)*(1.0f/RCUT);
    }
    float inv_rp = 1.0f/(r+FEPS);
    float w = PREF*fc*inv_rp;
    float s1,c1; __sincosf(PI_R*r, &s1, &c1);
    float sn[8], cn[8];
    {
        float sp_=0.f, sc=s1, cp_=1.f, cc=c1; const float c2=2.f*c1;
        #pragma unroll
        for(int m=0;m<8;m++){
            sn[m]=sc; cn[m]=cc;
            float nx=c2*sc-sp_; sp_=sc; sc=nx;
            float ncx=c2*cc-cp_; cp_=cc; cc=ncx;
        }
    }

    // forward, keeping silu-derivative factors
    const float* W1 = rW1 + l*256;  const float* B1 = rb1 + l*32;
    float df1[32], h1[32];
    #pragma unroll
    for(int k=0;k<32;k++){
        float a = B1[k];
        #pragma unroll
        for(int q=0;q<8;q++) a += (sn[q]*w)*W1[k*8+q];
        float sg=sigm(a); h1[k]=a*sg; df1[k]=sg*(1.f + a*(1.f-sg));
    }
    const float* W2 = rW2 + l*1024; const float* B2 = rb2 + l*32;
    float df2[32], h2[32];
    #pragma unroll
    for(int j=0;j<32;j++){
        float a = B2[j];
        #pragma unroll
        for(int k=0;k<32;k++) a += h1[k]*W2[j*32+k];
        float sg=sigm(a); h2[j]=a*sg; df2[j]=sg*(1.f + a*(1.f-sg));
    }
    const float* W3 = rW3 + l*1024; const float* B3 = rb3 + l*32;
    const int sp = species[s];
    float RlZ[32];
    #pragma unroll
    for(int j=0;j<32;j++){
        float a = B3[j];
        #pragma unroll
        for(int k=0;k<32;k++) a += h2[k]*W3[j*32+k];
        RlZ[j] = a * Wz[j*3+sp];
    }
    float dRlZ[32];
    #pragma unroll
    for(int k=0;k<32;k++) dRlZ[k]=0.f;
    float dux=0.f, duy=0.f, duz=0.f;
    #define ROW(I, YV, DX, DY, DZ) { \
        const float yv=(YV); float dY=0.f; \
        _Pragma("unroll") \
        for(int k=0;k<32;k++){ \
            float g = NM ? dA[(size_t)t*512 + (I)*32 + k] : dA[((I)*32+k)*NN + t]; \
            dRlZ[k] += g*yv; dY += g*RlZ[k]; } \
        dux += dY*(DX); duy += dY*(DY); duz += dY*(DZ); }
    if (l==0){
        ROW(0, 1.0f, 0.f,0.f,0.f)
    } else if (l==1){
        ROW(1, 1.7320508f*x, 1.7320508f, 0.f, 0.f)
        ROW(2, 1.7320508f*y, 0.f, 1.7320508f, 0.f)
        ROW(3, 1.7320508f*z, 0.f, 0.f, 1.7320508f)
    } else if (l==2){
        ROW(4, 3.8729833f*x*y, 3.8729833f*y, 3.8729833f*x, 0.f)
        ROW(5, 3.8729833f*y*z, 0.f, 3.8729833f*z, 3.8729833f*y)
        ROW(6, 1.1180340f*(3.f*z*z-1.f), 0.f, 0.f, 6.7082039f*z)
        ROW(7, 3.8729833f*x*z, 3.8729833f*z, 0.f, 3.8729833f*x)
        ROW(8, 1.9364917f*(x*x-y*y), 3.8729833f*x, -3.8729833f*y, 0.f)
    } else {
        ROW(9,  2.0916501f*y*(3.f*x*x-y*y), 12.549901f*x*y, 2.0916501f*(3.f*x*x-3.f*y*y), 0.f)
        ROW(10, 10.246951f*x*y*z, 10.246951f*y*z, 10.246951f*x*z, 10.246951f*x*y)
        ROW(11, 1.6201852f*y*(5.f*z*z-1.f), 0.f, 1.6201852f*(5.f*z*z-1.f), 16.201852f*y*z)
        ROW(12, 1.3228757f*(5.f*z*z*z-3.f*z), 0.f, 0.f, 1.3228757f*(15.f*z*z-3.f))
        ROW(13, 1.6201852f*x*(5.f*z*z-1.f), 1.6201852f*(5.f*z*z-1.f), 0.f, 16.201852f*x*z)
        ROW(14, 5.1234754f*z*(x*x-y*y), 10.246951f*x*z, -10.246951f*y*z, 5.1234754f*(x*x-y*y))
        ROW(15, 2.0916501f*x*(x*x-3.f*y*y), 2.0916501f*(3.f*x*x-3.f*y*y), -12.549901f*x*y, 0.f)
    }
    #undef ROW
    #pragma unroll
    for(int j=0;j<32;j++) dRlZ[j] *= Wz[j*3+sp];
    float dz2[32];
    #pragma unroll
    for(int k=0;k<32;k++){
        float a=0.f;
        #pragma unroll
        for(int j=0;j<32;j++) a += dRlZ[j]*W3[j*32+k];
        dz2[k] = a*df2[k];
    }
    float dz1[32];
    #pragma unroll
    for(int k=0;k<32;k++){
        float a=0.f;
        #pragma unroll
        for(int j=0;j<32;j++) a += dz2[j]*W2[j*32+k];
        dz1[k] = a*df1[k];
    }
    float gr = 0.f;
    #pragma unroll
    for(int m=0;m<8;m++){
        float a=0.f;
        #pragma unroll
        for(int k=0;k<32;k++) a += dz1[k]*W1[k*8+m];
        float b  = PREF*sn[m]*inv_rp;
        float db = PREF*((float)(m+1)*PI_R*cn[m]*(r+FEPS) - sn[m])*inv_rp*inv_rp;
        gr += a*(db*fc + b*dfc);
    }
    float udd = x*dux + y*duy + z*duz;
    float gx = gr*x + (dux - x*udd)*inv_r;
    float gy = gr*y + (duy - y*udd)*inv_r;
    float gz = gr*z + (duz - z*udd)*inv_r;
    if (NM){
        fout[(l*3+0)*NE + idx] = gx;
        fout[(l*3+1)*NE + idx] = gy;
        fout[(l*3+2)*NE + idx] = gz;
    } else {
        atomicAdd(&fout[3*t+0], -gx); atomicAdd(&fout[3*t+1], -gy); atomicAdd(&fout[3*t+2], -gz);
        atomicAdd(&fout[3*s+0],  gx); atomicAdd(&fout[3*s+1],  gy); atomicAdd(&fout[3*s+2],  gz);
    }
}

// ================= force reduce: t-side gather (no atomics) ==================
__global__ __launch_bounds__(256) void freduce_t(
    const float* __restrict__ fbuf, const int* __restrict__ roff,
    float* __restrict__ F)
{
    int n = blockIdx.x*256 + threadIdx.x;
    if (n >= NN) return;
    float gx=0.f, gy=0.f, gz=0.f;
    const int beg = roff[n], end = roff[n+1];
    for (int idx=beg; idx<end; ++idx){
        gx += fbuf[0*NE+idx] + fbuf[3*NE+idx] + fbuf[6*NE+idx] + fbuf[ 9*NE+idx];
        gy += fbuf[1*NE+idx] + fbuf[4*NE+idx] + fbuf[7*NE+idx] + fbuf[10*NE+idx];
        gz += fbuf[2*NE+idx] + fbuf[5*NE+idx] + fbuf[8*NE+idx] + fbuf[11*NE+idx];
    }
    F[3*n+0] = -gx; F[3*n+1] = -gy; F[3*n+2] = -gz;
}

// ================= force reduce: s-side scatter (atomics) ====================
__global__ __launch_bounds__(256) void freduce_s(
    const float* __restrict__ fbuf, const int* __restrict__ eidx,
    const int* __restrict__ elist, float* __restrict__ F)
{
    int idx = blockIdx.x*256 + threadIdx.x;
    if (idx >= NE) return;
    int e = elist[idx];
    int s = eidx[e];
    float gx = fbuf[0*NE+idx] + fbuf[3*NE+idx] + fbuf[6*NE+idx] + fbuf[ 9*NE+idx];
    float gy = fbuf[1*NE+idx] + fbuf[4*NE+idx] + fbuf[7*NE+idx] + fbuf[10*NE+idx];
    float gz = fbuf[2*NE+idx] + fbuf[5*NE+idx] + fbuf[8*NE+idx] + fbuf[11*NE+idx];
    atomicAdd(&F[3*s+0], gx); atomicAdd(&F[3*s+1], gy); atomicAdd(&F[3*s+2], gz);
}

// ================= fallback: round-1 atomic edge forward =====================
__global__ __launch_bounds__(256) void edge_fwd_fb(
    const float* __restrict__ pos, const int* __restrict__ eidx,
    const float* __restrict__ shifts, const int* __restrict__ species,
    const float* __restrict__ Wz,
    const float* __restrict__ rW1, const float* __restrict__ rb1,
    const float* __restrict__ rW2, const float* __restrict__ rb2,
    const float* __restrict__ rW3, const float* __restrict__ rb3,
    float* __restrict__ A_t)
{
    const int e = blockIdx.x*256 + threadIdx.x;
    const int l = blockIdx.y;
    if (e >= NE) return;
    const int s = eidx[e];
    const int t = eidx[NE + e];
    float vx = pos[3*t+0]-pos[3*s+0]+shifts[3*e+0];
    float vy = pos[3*t+1]-pos[3*s+1]+shifts[3*e+1];
    float vz = pos[3*t+2]-pos[3*s+2]+shifts[3*e+2];
    float r2 = vx*vx+vy*vy+vz*vz + FEPS;
    float r  = sqrtf(r2);
    float inv_r = 1.0f/r;
    float x = vx*inv_r, y = vy*inv_r, z = vz*inv_r;
    float tt = r*(1.0f/RCUT);
    float fcv = 0.0f;
    if (r < RCUT){
        float t2=tt*tt, t3=t2*tt, t6=t3*t3;
        fcv = 1.0f + t6*(-28.0f + tt*(48.0f - 21.0f*tt));
    }
    float inv_rp = 1.0f/(r+FEPS);
    float w = PREF*fcv*inv_rp;
    float s1,c1; __sincosf(PI_R*r, &s1, &c1);
    float xr[8];
    {
        float sp_=0.f, sc=s1; const float c2=2.f*c1;
        #pragma unroll
        for(int m=0;m<8;m++){ xr[m]=sc*w; float nx=c2*sc-sp_; sp_=sc; sc=nx; }
    }
    const float* W1 = rW1 + l*256;  const float* B1 = rb1 + l*32;
    float h1[32];
    #pragma unroll
    for(int k=0;k<32;k++){
        float a = B1[k];
        #pragma unroll
        for(int q=0;q<8;q++) a += xr[q]*W1[k*8+q];
        h1[k] = a*sigm(a);
    }
    const float* W2 = rW2 + l*1024; const float* B2 = rb2 + l*32;
    float h2[32];
    #pragma unroll
    for(int j=0;j<32;j++){
        float a = B2[j];
        #pragma unroll
        for(int k=0;k<32;k++) a += h1[k]*W2[j*32+k];
        h2[j] = a*sigm(a);
    }
    const float* W3 = rW3 + l*1024; const float* B3 = rb3 + l*32;
    const int sp = species[s];
    float RlZ[32];
    #pragma unroll
    for(int j=0;j<32;j++){
        float a = B3[j];
        #pragma unroll
        for(int k=0;k<32;k++) a += h2[k]*W3[j*32+k];
        RlZ[j] = a * Wz[j*3+sp];
    }
    #define ACCI(I, YV) { const float yv=(YV); \
        _Pragma("unroll") \
        for(int k=0;k<32;k++) atomicAdd(&A_t[((I)*32+k)*NN + t], RlZ[k]*yv); }
    if (l==0){
        ACCI(0, 1.0f)
    } else if (l==1){
        ACCI(1, 1.7320508f*x) ACCI(2, 1.7320508f*y) ACCI(3, 1.7320508f*z)
    } else if (l==2){
        ACCI(4, 3.8729833f*x*y) ACCI(5, 3.8729833f*y*z)
        ACCI(6, 1.1180340f*(3.f*z*z-1.f)) ACCI(7, 3.8729833f*x*z)
        ACCI(8, 1.9364917f*(x*x-y*y))
    } else {
        ACCI(9,  2.0916501f*y*(3.f*x*x-y*y))
        ACCI(10, 10.246951f*x*y*z)
        ACCI(11, 1.6201852f*y*(5.f*z*z-1.f))
        ACCI(12, 1.3228757f*(5.f*z*z*z-3.f*z))
        ACCI(13, 1.6201852f*x*(5.f*z*z-1.f))
        ACCI(14, 5.1234754f*z*(x*x-y*y))
        ACCI(15, 2.0916501f*x*(x*x-3.f*y*y))
    }
    #undef ACCI
}

// ================= launcher =================
extern "C" void kernel_launch(void* const* d_in, const int* in_sizes, int n_in,
                              void* d_out, int out_size, void* d_ws, size_t ws_size,
                              hipStream_t stream)
{
    const float* pos    = (const float*)d_in[0];
    const int*   eidx   = (const int*)  d_in[1];
    const float* shifts = (const float*)d_in[2];
    const int*   spec   = (const int*)  d_in[3];
    const int*   batch  = (const int*)  d_in[4];
    const float* Wz     = (const float*)d_in[5];
    const float* rW1    = (const float*)d_in[6];
    const float* rb1    = (const float*)d_in[7];
    const float* rW2    = (const float*)d_in[8];
    const float* rb2    = (const float*)d_in[9];
    const float* rW3    = (const float*)d_in[10];
    const float* rb3    = (const float*)d_in[11];
    const float* mixW   = (const float*)d_in[12];
    const float* symW1  = (const float*)d_in[13];
    const float* symW2  = (const float*)d_in[14];
    const float* eW     = (const float*)d_in[15];
    const float* ebp    = (const float*)d_in[16];
    const float* e0W    = (const float*)d_in[17];
    const float* e0b    = (const float*)d_in[18];
    float* out = (float*)d_out;

    // workspace: ints [deg NN | roff NN+1 | woff NN | elist NE], then floats
    // [A_t 512*NN | E_node NN | fbuf 12*NE | msg 144*NE]
    // einv (NE ints) aliases fbuf; dA_n (512*NN) aliases msg
    const size_t INTS   = (size_t)(3*NN + 1 + NE);
    const size_t FOFF   = ((INTS*4 + 255)/256)*256;
    const size_t NEEDED = FOFF + ((size_t)512*NN + NN + (size_t)12*NE + (size_t)144*NE)*4;

    if (ws_size >= NEEDED){
        int*   deg    = (int*)d_ws;
        int*   roff   = deg + NN;
        int*   woff   = roff + NN + 1;
        int*   elist  = woff + NN;
        float* f0     = (float*)((char*)d_ws + FOFF);
        float* A_t    = f0;
        float* E_node = A_t + (size_t)512*NN;
        float* fbuf   = E_node + NN;
        float* msg    = fbuf + (size_t)12*NE;
        float* dA_n   = msg;            // alias: msg dead after gather
        int*   einv   = (int*)fbuf;     // alias: einv dead before fbuf written

        hipMemsetAsync(deg, 0, NN*sizeof(int), stream);
        hipMemsetAsync(E_node, 0, NN*sizeof(float), stream);
        hipMemsetAsync(d_out, 0, (size_t)out_size*sizeof(float), stream);

        csr_count  <<<(NE+255)/256, 256, 0, stream>>>(eidx, deg);
        csr_scan   <<<1, 256, 0, stream>>>(deg, roff, woff);
        csr_scatter<<<(NE+255)/256, 256, 0, stream>>>(eidx, woff, elist, einv);
        edge_compute<<<(NE+255)/256, 256, 0, stream>>>(pos, eidx, shifts, spec, Wz,
                                                       rW1, rb1, rW2, rb2, rW3, rb3,
                                                       einv, msg);
        gather<<<(NN*64+255)/256, 256, 0, stream>>>(msg, roff, A_t);
        dim3 ng((NN+255)/256, 16);
        node_pass<true><<<ng, 256, 0, stream>>>(A_t, spec, mixW, symW1, symW2,
                                                eW, ebp, e0W, e0b, dA_n, E_node);
        ereduce<<<(NN+255)/256, 256, 0, stream>>>(E_node, batch, out);
        edge_bwd<true><<<NXB*4, 256, 0, stream>>>(pos, eidx, shifts, spec, Wz,
                                                  rW1, rb1, rW2, rb2, rW3, rb3,
                                                  dA_n, elist, fbuf);
        freduce_t<<<(NN+255)/256, 256, 0, stream>>>(fbuf, roff, out + NG);
        freduce_s<<<(NE+255)/256, 256, 0, stream>>>(fbuf, eidx, elist, out + NG);
    } else {
        // fallback: round-1 path (requires 41 MB, known-good)
        float* A_t    = (float*)d_ws;
        float* E_node = A_t + (size_t)512*NN;
        float* dA_t   = E_node + NN;
        hipMemsetAsync(d_ws, 0, ((size_t)512*NN + NN)*sizeof(float), stream);
        hipMemsetAsync(d_out, 0, (size_t)out_size*sizeof(float), stream);
        dim3 eg((NE+255)/256, 4);
        edge_fwd_fb<<<eg, 256, 0, stream>>>(pos, eidx, shifts, spec, Wz,
                                            rW1, rb1, rW2, rb2, rW3, rb3, A_t);
        dim3 ng((NN+255)/256, 16);
        node_pass<false><<<ng, 256, 0, stream>>>(A_t, spec, mixW, symW1, symW2,
                                                 eW, ebp, e0W, e0b, dA_t, E_node);
        ereduce<<<(NN+255)/256, 256, 0, stream>>>(E_node, batch, out);
        dim3 eg2((NE+255)/256, 4);
        edge_bwd<false><<<eg2, 256, 0, stream>>>(pos, eidx, shifts, spec, Wz,
                                                 rW1, rb1, rW2, rb2, rW3, rb3,
                                                 dA_t, nullptr, out + NG);
    }
}